// Round 1
// baseline (623.999 us; speedup 1.0000x reference)
//
#include <hip/hip_runtime.h>
#include <math.h>

#define N_NODES 50000
#define N_EDGES 500000
#define IN_DIM 256
#define OUT_DIM 128
#define NEG_SLOPE 0.01f

// ---------------- GEMM: z[n][o] = sum_k h[n][k] * W[o][k] ----------------
// 64-row x 128-col tile, K staged 32 at a time. Pad 36 floats/row: all inner
// LDS reads land as 2-way conflicts (free on CDNA4).
__global__ __launch_bounds__(256) void gemm_kernel(
    const float* __restrict__ h, const float* __restrict__ W,
    float* __restrict__ z) {
  __shared__ float As[64][36];
  __shared__ float Bs[128][36];
  const int t  = threadIdx.x;
  const int tx = t & 15, ty = t >> 4;
  const int row0 = blockIdx.x * 64;

  float acc[4][8];
#pragma unroll
  for (int i = 0; i < 4; ++i)
#pragma unroll
    for (int j = 0; j < 8; ++j) acc[i][j] = 0.f;

  for (int kk = 0; kk < IN_DIM; kk += 32) {
    // stage A: 64 rows x 32 k  (512 float4, 2 per thread)
#pragma unroll
    for (int q = 0; q < 2; ++q) {
      int s = t * 2 + q;
      int r = s >> 3, c4 = s & 7;
      int gr = row0 + r;
      float4 v = make_float4(0.f, 0.f, 0.f, 0.f);
      if (gr < N_NODES)
        v = *(const float4*)&h[(size_t)gr * IN_DIM + kk + c4 * 4];
      *(float4*)&As[r][c4 * 4] = v;
    }
    // stage B: 128 rows x 32 k (1024 float4, 4 per thread)
#pragma unroll
    for (int q = 0; q < 4; ++q) {
      int s = t * 4 + q;
      int r = s >> 3, c4 = s & 7;
      float4 v = *(const float4*)&W[(size_t)r * IN_DIM + kk + c4 * 4];
      *(float4*)&Bs[r][c4 * 4] = v;
    }
    __syncthreads();

#pragma unroll
    for (int k4 = 0; k4 < 8; ++k4) {
      float4 a[4], b[8];
#pragma unroll
      for (int i = 0; i < 4; ++i) a[i] = *(const float4*)&As[ty * 4 + i][k4 * 4];
#pragma unroll
      for (int j = 0; j < 8; ++j) b[j] = *(const float4*)&Bs[tx + 16 * j][k4 * 4];
#pragma unroll
      for (int i = 0; i < 4; ++i)
#pragma unroll
        for (int j = 0; j < 8; ++j) {
          acc[i][j] += a[i].x * b[j].x + a[i].y * b[j].y +
                       a[i].z * b[j].z + a[i].w * b[j].w;
        }
    }
    __syncthreads();
  }

#pragma unroll
  for (int i = 0; i < 4; ++i) {
    int gr = row0 + ty * 4 + i;
    if (gr >= N_NODES) continue;
#pragma unroll
    for (int j = 0; j < 8; ++j)
      z[(size_t)gr * OUT_DIM + tx + 16 * j] = acc[i][j];
  }
}

// ---------------- per-node attention scalars ----------------
// s1[n] = z[n] . aw[0:128],  s2[n] = z[n] . aw[128:256]
__global__ __launch_bounds__(256) void s_kernel(
    const float* __restrict__ z, const float* __restrict__ aw,
    float* __restrict__ s1, float* __restrict__ s2) {
  const int wid = threadIdx.x >> 6, lane = threadIdx.x & 63;
  const int n = blockIdx.x * 4 + wid;
  if (n >= N_NODES) return;
  const float* zr = z + (size_t)n * OUT_DIM;
  float z0 = zr[lane], z1 = zr[lane + 64];
  float a1 = z0 * aw[lane] + z1 * aw[lane + 64];
  float a2 = z0 * aw[128 + lane] + z1 * aw[192 + lane];
#pragma unroll
  for (int off = 32; off; off >>= 1) {
    a1 += __shfl_down(a1, off);
    a2 += __shfl_down(a2, off);
  }
  if (lane == 0) { s1[n] = a1; s2[n] = a2; }
}

// ---------------- exact integer mean of dist ----------------
__global__ __launch_bounds__(256) void mean_kernel(
    const int* __restrict__ dist, int* __restrict__ isum) {
  int tid = blockIdx.x * blockDim.x + threadIdx.x;
  int stride = gridDim.x * blockDim.x;
  int acc = 0;
  for (int i = tid; i < N_EDGES; i += stride) acc += dist[i];
#pragma unroll
  for (int off = 32; off; off >>= 1) acc += __shfl_down(acc, off);
  if ((threadIdx.x & 63) == 0) atomicAdd(isum, acc);
}

__device__ __forceinline__ unsigned float_key(float f) {
  unsigned b = __float_as_uint(f);
  return (b & 0x80000000u) ? ~b : (b | 0x80000000u);
}
__device__ __forceinline__ float key_float(unsigned u) {
  unsigned b = (u & 0x80000000u) ? (u & 0x7FFFFFFFu) : ~u;
  return __uint_as_float(b);
}

// ---------------- edge pass 1: e = pmf * leaky(a); segment max ----------------
__global__ __launch_bounds__(256) void edge1_kernel(
    const float* __restrict__ s1, const float* __restrict__ s2,
    const int* __restrict__ src, const int* __restrict__ dst,
    const int* __restrict__ dist, const int* __restrict__ isum,
    float* __restrict__ e, unsigned* __restrict__ maxkey) {
  int i = blockIdx.x * blockDim.x + threadIdx.x;
  if (i >= N_EDGES) return;
  float mu = (float)(*isum) * (1.0f / N_EDGES);
  float df = (float)dist[i];
  float k = floorf(df * 0.5f);
  float logp = k * logf(mu) - mu - lgammaf(k + 1.0f);
  float p = expf(logp);
  float a = s1[src[i]] + s2[dst[i]];
  float lr = (a >= 0.f) ? a : NEG_SLOPE * a;
  float ev = p * lr;
  e[i] = ev;
  atomicMax(&maxkey[dst[i]], float_key(ev));
}

// ---------------- edge pass 2: ex = exp(e - m[dst]); segment sum ----------------
__global__ __launch_bounds__(256) void edge2_kernel(
    float* __restrict__ e, const int* __restrict__ dst,
    const unsigned* __restrict__ maxkey, float* __restrict__ denom) {
  int i = blockIdx.x * blockDim.x + threadIdx.x;
  if (i >= N_EDGES) return;
  int d = dst[i];
  float m = key_float(maxkey[d]);
  float ex = expf(e[i] - m);
  e[i] = ex;
  atomicAdd(&denom[d], ex);
}

// ---------------- scatter: out[dst] += alpha * z[src] ----------------
// one wave per edge; lane handles 2 contiguous features (float2 gather).
__global__ __launch_bounds__(256) void scatter_kernel(
    const float* __restrict__ ex, const float* __restrict__ denom,
    const int* __restrict__ src, const int* __restrict__ dst,
    const float* __restrict__ z, float* __restrict__ out) {
  const int wid = threadIdx.x >> 6, lane = threadIdx.x & 63;
  const int i = blockIdx.x * 4 + wid;
  if (i >= N_EDGES) return;
  const int s = src[i], d = dst[i];
  const float alpha = ex[i] / denom[d];
  const float2 zv = *(const float2*)&z[(size_t)s * OUT_DIM + lane * 2];
  float* orow = out + (size_t)d * OUT_DIM;
  atomicAdd(&orow[lane * 2 + 0], alpha * zv.x);
  atomicAdd(&orow[lane * 2 + 1], alpha * zv.y);
}

extern "C" void kernel_launch(void* const* d_in, const int* in_sizes, int n_in,
                              void* d_out, int out_size, void* d_ws, size_t ws_size,
                              hipStream_t stream) {
  const float* h     = (const float*)d_in[0];
  const float* fc_w  = (const float*)d_in[1];
  const float* attn  = (const float*)d_in[2];
  const int*   src   = (const int*)d_in[3];
  const int*   dst   = (const int*)d_in[4];
  const int*   dist  = (const int*)d_in[5];
  float* out = (float*)d_out;
  float* ws  = (float*)d_ws;

  // workspace layout (floats)
  float*    z      = ws;                     // 6,400,000
  float*    s1     = ws + 6400000;           //    50,000
  float*    s2     = ws + 6450000;           //    50,000
  float*    e      = ws + 6500000;           //   500,000 (reused as ex)
  unsigned* maxkey = (unsigned*)(ws + 7000000); // 50,000
  float*    denom  = ws + 7050000;           //    50,000
  int*      isum   = (int*)(ws + 7100000);   //         1

  // zero the accumulators (maxkey+denom+isum contiguous) and the output
  hipMemsetAsync(ws + 7000000, 0, (size_t)(100001) * sizeof(float), stream);
  hipMemsetAsync(d_out, 0, (size_t)out_size * sizeof(float), stream);

  gemm_kernel<<<(N_NODES + 63) / 64, 256, 0, stream>>>(h, fc_w, z);
  s_kernel<<<(N_NODES + 3) / 4, 256, 0, stream>>>(z, attn, s1, s2);
  mean_kernel<<<256, 256, 0, stream>>>(dist, isum);
  edge1_kernel<<<(N_EDGES + 255) / 256, 256, 0, stream>>>(
      s1, s2, src, dst, dist, isum, e, maxkey);
  edge2_kernel<<<(N_EDGES + 255) / 256, 256, 0, stream>>>(e, dst, maxkey, denom);
  scatter_kernel<<<(N_EDGES + 3) / 4, 256, 0, stream>>>(
      e, denom, src, dst, z, out);
}

// Round 7
// 317.698 us; speedup vs baseline: 1.9641x; 1.9641x over previous
//
#include <hip/hip_runtime.h>
#include <math.h>

#define N_NODES 50000
#define N_EDGES 500000
#define IN_DIM 256
#define OUT_DIM 128
#define NEG_SLOPE 0.01f

// ---------------- GEMM: z[n][o] = sum_k h[n][k] * W[o][k] ----------------
// 64-row x 128-col tile, K staged 32 at a time. Pad 36 floats/row.
// Epilogue also computes s1[n] = z[n].aw[0:128], s2[n] = z[n].aw[128:256]
// (16-lane shuffle reduce; each row is owned by the 16 threads with equal ty).
__global__ __launch_bounds__(256) void gemm_kernel(
    const float* __restrict__ h, const float* __restrict__ W,
    const float* __restrict__ aw,
    float* __restrict__ z, float* __restrict__ s1, float* __restrict__ s2) {
  __shared__ float As[64][36];
  __shared__ float Bs[128][36];
  const int t  = threadIdx.x;
  const int tx = t & 15, ty = t >> 4;
  const int row0 = blockIdx.x * 64;

  float acc[4][8];
#pragma unroll
  for (int i = 0; i < 4; ++i)
#pragma unroll
    for (int j = 0; j < 8; ++j) acc[i][j] = 0.f;

  for (int kk = 0; kk < IN_DIM; kk += 32) {
#pragma unroll
    for (int q = 0; q < 2; ++q) {
      int s = t * 2 + q;
      int r = s >> 3, c4 = s & 7;
      int gr = row0 + r;
      float4 v = make_float4(0.f, 0.f, 0.f, 0.f);
      if (gr < N_NODES)
        v = *(const float4*)&h[(size_t)gr * IN_DIM + kk + c4 * 4];
      *(float4*)&As[r][c4 * 4] = v;
    }
#pragma unroll
    for (int q = 0; q < 4; ++q) {
      int s = t * 4 + q;
      int r = s >> 3, c4 = s & 7;
      float4 v = *(const float4*)&W[(size_t)r * IN_DIM + kk + c4 * 4];
      *(float4*)&Bs[r][c4 * 4] = v;
    }
    __syncthreads();

#pragma unroll
    for (int k4 = 0; k4 < 8; ++k4) {
      float4 a[4], b[8];
#pragma unroll
      for (int i = 0; i < 4; ++i) a[i] = *(const float4*)&As[ty * 4 + i][k4 * 4];
#pragma unroll
      for (int j = 0; j < 8; ++j) b[j] = *(const float4*)&Bs[tx + 16 * j][k4 * 4];
#pragma unroll
      for (int i = 0; i < 4; ++i)
#pragma unroll
        for (int j = 0; j < 8; ++j) {
          acc[i][j] += a[i].x * b[j].x + a[i].y * b[j].y +
                       a[i].z * b[j].z + a[i].w * b[j].w;
        }
    }
    __syncthreads();
  }

#pragma unroll
  for (int i = 0; i < 4; ++i) {
    int gr = row0 + ty * 4 + i;
    if (gr >= N_NODES) continue;
    float p1 = 0.f, p2 = 0.f;
#pragma unroll
    for (int j = 0; j < 8; ++j) {
      float v = acc[i][j];
      z[(size_t)gr * OUT_DIM + tx + 16 * j] = v;
      p1 += v * aw[tx + 16 * j];
      p2 += v * aw[128 + tx + 16 * j];
    }
    // reduce across the 16 threads (same ty) that own this row
#pragma unroll
    for (int off = 8; off; off >>= 1) {
      p1 += __shfl_xor(p1, off);
      p2 += __shfl_xor(p2, off);
    }
    if (tx == 0) { s1[gr] = p1; s2[gr] = p2; }
  }
}

// ---------------- fused: exact integer mean of dist + dst histogram ----------------
__global__ __launch_bounds__(256) void mean_hist_kernel(
    const int* __restrict__ dist, const int* __restrict__ dst,
    int* __restrict__ isum, int* __restrict__ cidx) {
  int tid = blockIdx.x * blockDim.x + threadIdx.x;
  int stride = gridDim.x * blockDim.x;
  int acc = 0;
  for (int i = tid; i < N_EDGES; i += stride) {
    acc += dist[i];
    atomicAdd(&cidx[dst[i]], 1);
  }
#pragma unroll
  for (int off = 32; off; off >>= 1) acc += __shfl_down(acc, off);
  if ((threadIdx.x & 63) == 0) atomicAdd(isum, acc);
}

// ---------------- single-block exclusive scan of 50000 counts (in place) ----------------
__global__ __launch_bounds__(1024) void scan_kernel(int* __restrict__ c) {
  __shared__ int sums[1024];
  const int t = threadIdx.x;
  const int base = t * 49;                 // 1024*49 = 50176 >= 50000
  const int lim = min(base + 49, N_NODES);
  int loc = 0;
  for (int i = base; i < lim; ++i) loc += c[i];
  sums[t] = loc;
  __syncthreads();
  for (int off = 1; off < 1024; off <<= 1) {
    int v = (t >= off) ? sums[t - off] : 0;
    __syncthreads();
    sums[t] += v;
    __syncthreads();
  }
  int run = sums[t] - loc;                 // exclusive prefix of this chunk
  for (int i = base; i < lim; ++i) {
    int cv = c[i];
    c[i] = run;                            // counts -> exclusive starts
    run += cv;
  }
}

// ---------------- fill: CSR edge-id list (cursor advances starts -> ends) ----------------
__global__ __launch_bounds__(256) void fill_kernel(
    const int* __restrict__ dst, int* __restrict__ cursor,
    int* __restrict__ eidx) {
  int i = blockIdx.x * blockDim.x + threadIdx.x;
  if (i >= N_EDGES) return;
  int pos = atomicAdd(&cursor[dst[i]], 1);
  eidx[pos] = i;
}

// ---------------- node kernel: one wave per dst node ----------------
// segment softmax over incoming edges + weighted gather-sum of z[src], no atomics.
// After fill_kernel, cidx[n] == end of segment n, so beg = cidx[n-1] (0 for n=0).
__global__ __launch_bounds__(256) void node_kernel(
    const float* __restrict__ s1, const float* __restrict__ s2,
    const int* __restrict__ src, const int* __restrict__ dist,
    const int* __restrict__ isum, const int* __restrict__ cidx,
    const int* __restrict__ eidx, const float* __restrict__ z,
    float* __restrict__ out) {
  const int wid = threadIdx.x >> 6, lane = threadIdx.x & 63;
  const int n = blockIdx.x * 4 + wid;
  if (n >= N_NODES) return;
  const int beg = (n == 0) ? 0 : cidx[n - 1];
  const int end = cidx[n];
  const int deg = end - beg;

  float2 acc = make_float2(0.f, 0.f);
  if (deg > 0) {
    const float mu = (float)(*isum) * (1.0f / N_EDGES);
    const float logmu = logf(mu);
    const float s2n = s2[n];

    if (deg <= 128) {
      // per-lane registers hold e, src, for edges j=lane and j=lane+64
      float e0 = -INFINITY, e1 = -INFINITY;
      int src0r = 0, src1r = 0;
#pragma unroll
      for (int half = 0; half < 2; ++half) {
        int j = lane + half * 64;
        if (j < deg) {
          int idx = eidx[beg + j];
          float df = (float)dist[idx];
          float k = floorf(df * 0.5f);
          float p = expf(k * logmu - mu - lgammaf(k + 1.0f));
          int sn = src[idx];
          float a = s1[sn] + s2n;
          float lr = (a >= 0.f) ? a : NEG_SLOPE * a;
          float ev = p * lr;
          if (half == 0) { e0 = ev; src0r = sn; }
          else           { e1 = ev; src1r = sn; }
        }
      }
      // wave max
      float m = fmaxf(e0, e1);
#pragma unroll
      for (int off = 32; off; off >>= 1) m = fmaxf(m, __shfl_xor(m, off));
      // exp + wave sum  (invalid lanes: e = -inf -> ex = 0)
      float ex0 = expf(e0 - m), ex1 = expf(e1 - m);
      float ssum = ex0 + ex1;
#pragma unroll
      for (int off = 32; off; off >>= 1) ssum += __shfl_xor(ssum, off);
      const float inv = 1.0f / ssum;
      const float a0 = ex0 * inv, a1 = ex1 * inv;
      // serial walk over edges; alpha/src broadcast via shuffle
      for (int jj = 0; jj < deg; ++jj) {
        float alpha = __shfl((jj < 64) ? a0 : a1, jj & 63);
        int   sidx  = __shfl((jj < 64) ? src0r : src1r, jj & 63);
        const float2 zv = *(const float2*)&z[(size_t)sidx * OUT_DIM + lane * 2];
        acc.x += alpha * zv.x;
        acc.y += alpha * zv.y;
      }
    } else {
      // generic fallback (statistically never at deg~Poisson(10))
      float m = -INFINITY;
      for (int j = lane; j < deg; j += 64) {
        int idx = eidx[beg + j];
        float df = (float)dist[idx];
        float k = floorf(df * 0.5f);
        float p = expf(k * logmu - mu - lgammaf(k + 1.0f));
        float a = s1[src[idx]] + s2n;
        float ev = p * ((a >= 0.f) ? a : NEG_SLOPE * a);
        m = fmaxf(m, ev);
      }
#pragma unroll
      for (int off = 32; off; off >>= 1) m = fmaxf(m, __shfl_xor(m, off));
      float ssum = 0.f;
      for (int j = lane; j < deg; j += 64) {
        int idx = eidx[beg + j];
        float df = (float)dist[idx];
        float k = floorf(df * 0.5f);
        float p = expf(k * logmu - mu - lgammaf(k + 1.0f));
        float a = s1[src[idx]] + s2n;
        float ev = p * ((a >= 0.f) ? a : NEG_SLOPE * a);
        ssum += expf(ev - m);
      }
#pragma unroll
      for (int off = 32; off; off >>= 1) ssum += __shfl_xor(ssum, off);
      const float inv = 1.0f / ssum;
      for (int jj = 0; jj < deg; ++jj) {
        int idx = eidx[beg + jj];
        float df = (float)dist[idx];
        float k = floorf(df * 0.5f);
        float p = expf(k * logmu - mu - lgammaf(k + 1.0f));
        int sidx = src[idx];
        float a = s1[sidx] + s2n;
        float ev = p * ((a >= 0.f) ? a : NEG_SLOPE * a);
        float alpha = expf(ev - m) * inv;
        const float2 zv = *(const float2*)&z[(size_t)sidx * OUT_DIM + lane * 2];
        acc.x += alpha * zv.x;
        acc.y += alpha * zv.y;
      }
    }
  }
  *(float2*)&out[(size_t)n * OUT_DIM + lane * 2] = acc;
}

extern "C" void kernel_launch(void* const* d_in, const int* in_sizes, int n_in,
                              void* d_out, int out_size, void* d_ws, size_t ws_size,
                              hipStream_t stream) {
  const float* h    = (const float*)d_in[0];
  const float* fc_w = (const float*)d_in[1];
  const float* attn = (const float*)d_in[2];
  const int*   src  = (const int*)d_in[3];
  const int*   dst  = (const int*)d_in[4];
  const int*   dist = (const int*)d_in[5];
  float* out = (float*)d_out;
  float* ws  = (float*)d_ws;

  // workspace layout (4-byte units), total 7,050,004 * 4B = 28.2 MB
  float* z    = ws;                         // 6,400,000 floats
  float* s1   = ws + 6400000;               //    50,000
  float* s2   = ws + 6450000;               //    50,000
  int*   cidx = (int*)(ws + 6500000);       //    50,000 (counts->starts->ends)
  int*   isum = (int*)(ws + 6550000);       //         1
  int*   eidx = (int*)(ws + 6550004);       //   500,000

  // zero cidx + isum (contiguous)
  hipMemsetAsync(cidx, 0, (size_t)50001 * sizeof(int), stream);

  gemm_kernel<<<(N_NODES + 63) / 64, 256, 0, stream>>>(h, fc_w, attn, z, s1, s2);
  mean_hist_kernel<<<256, 256, 0, stream>>>(dist, dst, isum, cidx);
  scan_kernel<<<1, 1024, 0, stream>>>(cidx);
  fill_kernel<<<(N_EDGES + 255) / 256, 256, 0, stream>>>(dst, cidx, eidx);
  node_kernel<<<(N_NODES + 3) / 4, 256, 0, stream>>>(
      s1, s2, src, dist, isum, cidx, eidx, z, out);
}

// Round 8
// 244.314 us; speedup vs baseline: 2.5541x; 1.3004x over previous
//
#include <hip/hip_runtime.h>
#include <math.h>

#define N_NODES 50000
#define N_EDGES 500000
#define IN_DIM 256
#define OUT_DIM 128
#define NEG_SLOPE 0.01f

typedef __attribute__((ext_vector_type(8))) short short8;
typedef __attribute__((ext_vector_type(4))) float f32x4;

// fp32 -> bf16 bits, round-to-nearest-even
__device__ __forceinline__ unsigned short f2bf(float f) {
  unsigned u = __float_as_uint(f);
  unsigned r = (u + 0x7FFFu + ((u >> 16) & 1u)) >> 16;
  return (unsigned short)r;
}

// ---------------- W fp32 -> bf16 (32768 elements, one-shot) ----------------
__global__ __launch_bounds__(256) void wconv_kernel(
    const float* __restrict__ W, unsigned short* __restrict__ Wb) {
  int i = blockIdx.x * 256 + threadIdx.x;
  Wb[i] = f2bf(W[i]);
}

// ---------------- MFMA GEMM: z = h @ W^T, fused s1/s2 epilogue ----------------
// No LDS, no barriers. Wave w of each block owns rows row0..row0+15; the wave
// computes all 128 cols as 8 col-tiles of 16x16x32 MFMAs over K=256.
// A-frag: lane holds h[row0+(l&15)][ks*32+(l>>4)*8 + 0..7]   (cvt fp32->bf16)
// B-frag: lane holds Wb[ct*16+(l&15)][ks*32+(l>>4)*8 + 0..7] (same pattern; any
//         consistent k-order is correct by A/B symmetry)
// C/D   : lane l, reg q -> row=(l>>4)*4+q, col=l&15   [m89-verified]
__global__ __launch_bounds__(256) void gemm_mfma_kernel(
    const float* __restrict__ h, const unsigned short* __restrict__ Wb,
    const float* __restrict__ aw,
    float* __restrict__ z, float* __restrict__ s1, float* __restrict__ s2) {
  const int wid  = threadIdx.x >> 6;
  const int lane = threadIdx.x & 63;
  const int row0 = blockIdx.x * 64 + wid * 16;
  const int r16  = lane & 15;
  const int kg   = lane >> 4;

  f32x4 acc[8];
#pragma unroll
  for (int ct = 0; ct < 8; ++ct) acc[ct] = (f32x4)(0.f);

  const int arow = row0 + r16;
  const size_t hbase = (size_t)((arow < N_NODES) ? arow : (N_NODES - 1)) * IN_DIM;

#pragma unroll 2
  for (int ks = 0; ks < 8; ++ks) {
    const int k0 = ks * 32 + kg * 8;
    const float4 a0 = *(const float4*)&h[hbase + k0];
    const float4 a1 = *(const float4*)&h[hbase + k0 + 4];
    short8 af;
    af[0] = (short)f2bf(a0.x); af[1] = (short)f2bf(a0.y);
    af[2] = (short)f2bf(a0.z); af[3] = (short)f2bf(a0.w);
    af[4] = (short)f2bf(a1.x); af[5] = (short)f2bf(a1.y);
    af[6] = (short)f2bf(a1.z); af[7] = (short)f2bf(a1.w);
#pragma unroll
    for (int ct = 0; ct < 8; ++ct) {
      const short8 bf = *(const short8*)&Wb[(size_t)(ct * 16 + r16) * IN_DIM + k0];
      acc[ct] = __builtin_amdgcn_mfma_f32_16x16x32_bf16(af, bf, acc[ct], 0, 0, 0);
    }
  }

  // store z: lane l, reg q -> row row0+(l>>4)*4+q, col ct*16+(l&15)
#pragma unroll
  for (int q = 0; q < 4; ++q) {
    const int zr = row0 + kg * 4 + q;
    if (zr < N_NODES) {
#pragma unroll
      for (int ct = 0; ct < 8; ++ct)
        z[(size_t)zr * OUT_DIM + ct * 16 + r16] = acc[ct][q];
    }
  }

  // fused s1/s2: per-lane partials over owned cols, xor-reduce the 16-lane group
  float p1[4] = {0.f, 0.f, 0.f, 0.f}, p2[4] = {0.f, 0.f, 0.f, 0.f};
#pragma unroll
  for (int ct = 0; ct < 8; ++ct) {
    const float w1 = aw[ct * 16 + r16];
    const float w2 = aw[128 + ct * 16 + r16];
#pragma unroll
    for (int q = 0; q < 4; ++q) {
      p1[q] += acc[ct][q] * w1;
      p2[q] += acc[ct][q] * w2;
    }
  }
#pragma unroll
  for (int off = 8; off; off >>= 1) {
#pragma unroll
    for (int q = 0; q < 4; ++q) {
      p1[q] += __shfl_xor(p1[q], off);
      p2[q] += __shfl_xor(p2[q], off);
    }
  }
  if (r16 == 0) {
#pragma unroll
    for (int q = 0; q < 4; ++q) {
      const int zr = row0 + kg * 4 + q;
      if (zr < N_NODES) { s1[zr] = p1[q]; s2[zr] = p2[q]; }
    }
  }
}

// ---------------- fused: exact integer mean of dist + dst histogram ----------------
__global__ __launch_bounds__(256) void mean_hist_kernel(
    const int* __restrict__ dist, const int* __restrict__ dst,
    int* __restrict__ isum, int* __restrict__ cidx) {
  int tid = blockIdx.x * blockDim.x + threadIdx.x;
  int stride = gridDim.x * blockDim.x;
  int acc = 0;
  for (int i = tid; i < N_EDGES; i += stride) {
    acc += dist[i];
    atomicAdd(&cidx[dst[i]], 1);
  }
#pragma unroll
  for (int off = 32; off; off >>= 1) acc += __shfl_down(acc, off);
  if ((threadIdx.x & 63) == 0) atomicAdd(isum, acc);
}

// ---------------- single-block exclusive scan of 50000 counts (in place) ----------------
__global__ __launch_bounds__(1024) void scan_kernel(int* __restrict__ c) {
  __shared__ int sums[1024];
  const int t = threadIdx.x;
  const int base = t * 49;                 // 1024*49 = 50176 >= 50000
  const int lim = min(base + 49, N_NODES);
  int loc = 0;
  for (int i = base; i < lim; ++i) loc += c[i];
  sums[t] = loc;
  __syncthreads();
  for (int off = 1; off < 1024; off <<= 1) {
    int v = (t >= off) ? sums[t - off] : 0;
    __syncthreads();
    sums[t] += v;
    __syncthreads();
  }
  int run = sums[t] - loc;                 // exclusive prefix of this chunk
  for (int i = base; i < lim; ++i) {
    int cv = c[i];
    c[i] = run;                            // counts -> exclusive starts
    run += cv;
  }
}

// ---------------- fill: CSR edge-id list (cursor advances starts -> ends) ----------------
__global__ __launch_bounds__(256) void fill_kernel(
    const int* __restrict__ dst, int* __restrict__ cursor,
    int* __restrict__ eidx) {
  int i = blockIdx.x * blockDim.x + threadIdx.x;
  if (i >= N_EDGES) return;
  int pos = atomicAdd(&cursor[dst[i]], 1);
  eidx[pos] = i;
}

// ---------------- node kernel: one wave per dst node ----------------
__global__ __launch_bounds__(256) void node_kernel(
    const float* __restrict__ s1, const float* __restrict__ s2,
    const int* __restrict__ src, const int* __restrict__ dist,
    const int* __restrict__ isum, const int* __restrict__ cidx,
    const int* __restrict__ eidx, const float* __restrict__ z,
    float* __restrict__ out) {
  const int wid = threadIdx.x >> 6, lane = threadIdx.x & 63;
  const int n = blockIdx.x * 4 + wid;
  if (n >= N_NODES) return;
  const int beg = (n == 0) ? 0 : cidx[n - 1];
  const int end = cidx[n];
  const int deg = end - beg;

  float2 acc = make_float2(0.f, 0.f);
  if (deg > 0) {
    const float mu = (float)(*isum) * (1.0f / N_EDGES);
    const float logmu = logf(mu);
    const float s2n = s2[n];

    if (deg <= 128) {
      float e0 = -INFINITY, e1 = -INFINITY;
      int src0r = 0, src1r = 0;
#pragma unroll
      for (int half = 0; half < 2; ++half) {
        int j = lane + half * 64;
        if (j < deg) {
          int idx = eidx[beg + j];
          float df = (float)dist[idx];
          float k = floorf(df * 0.5f);
          float p = expf(k * logmu - mu - lgammaf(k + 1.0f));
          int sn = src[idx];
          float a = s1[sn] + s2n;
          float lr = (a >= 0.f) ? a : NEG_SLOPE * a;
          float ev = p * lr;
          if (half == 0) { e0 = ev; src0r = sn; }
          else           { e1 = ev; src1r = sn; }
        }
      }
      float m = fmaxf(e0, e1);
#pragma unroll
      for (int off = 32; off; off >>= 1) m = fmaxf(m, __shfl_xor(m, off));
      float ex0 = expf(e0 - m), ex1 = expf(e1 - m);
      float ssum = ex0 + ex1;
#pragma unroll
      for (int off = 32; off; off >>= 1) ssum += __shfl_xor(ssum, off);
      const float inv = 1.0f / ssum;
      const float a0 = ex0 * inv, a1 = ex1 * inv;
      for (int jj = 0; jj < deg; ++jj) {
        float alpha = __shfl((jj < 64) ? a0 : a1, jj & 63);
        int   sidx  = __shfl((jj < 64) ? src0r : src1r, jj & 63);
        const float2 zv = *(const float2*)&z[(size_t)sidx * OUT_DIM + lane * 2];
        acc.x += alpha * zv.x;
        acc.y += alpha * zv.y;
      }
    } else {
      float m = -INFINITY;
      for (int j = lane; j < deg; j += 64) {
        int idx = eidx[beg + j];
        float df = (float)dist[idx];
        float k = floorf(df * 0.5f);
        float p = expf(k * logmu - mu - lgammaf(k + 1.0f));
        float a = s1[src[idx]] + s2n;
        float ev = p * ((a >= 0.f) ? a : NEG_SLOPE * a);
        m = fmaxf(m, ev);
      }
#pragma unroll
      for (int off = 32; off; off >>= 1) m = fmaxf(m, __shfl_xor(m, off));
      float ssum = 0.f;
      for (int j = lane; j < deg; j += 64) {
        int idx = eidx[beg + j];
        float df = (float)dist[idx];
        float k = floorf(df * 0.5f);
        float p = expf(k * logmu - mu - lgammaf(k + 1.0f));
        float a = s1[src[idx]] + s2n;
        float ev = p * ((a >= 0.f) ? a : NEG_SLOPE * a);
        ssum += expf(ev - m);
      }
#pragma unroll
      for (int off = 32; off; off >>= 1) ssum += __shfl_xor(ssum, off);
      const float inv = 1.0f / ssum;
      for (int jj = 0; jj < deg; ++jj) {
        int idx = eidx[beg + jj];
        float df = (float)dist[idx];
        float k = floorf(df * 0.5f);
        float p = expf(k * logmu - mu - lgammaf(k + 1.0f));
        int sidx = src[idx];
        float a = s1[sidx] + s2n;
        float ev = p * ((a >= 0.f) ? a : NEG_SLOPE * a);
        float alpha = expf(ev - m) * inv;
        const float2 zv = *(const float2*)&z[(size_t)sidx * OUT_DIM + lane * 2];
        acc.x += alpha * zv.x;
        acc.y += alpha * zv.y;
      }
    }
  }
  *(float2*)&out[(size_t)n * OUT_DIM + lane * 2] = acc;
}

extern "C" void kernel_launch(void* const* d_in, const int* in_sizes, int n_in,
                              void* d_out, int out_size, void* d_ws, size_t ws_size,
                              hipStream_t stream) {
  const float* h    = (const float*)d_in[0];
  const float* fc_w = (const float*)d_in[1];
  const float* attn = (const float*)d_in[2];
  const int*   src  = (const int*)d_in[3];
  const int*   dst  = (const int*)d_in[4];
  const int*   dist = (const int*)d_in[5];
  float* out = (float*)d_out;
  float* ws  = (float*)d_ws;

  // workspace layout (4-byte units), total 7,066,388 * 4B = 28.3 MB
  float*          z    = ws;                          // 6,400,000 floats
  float*          s1   = ws + 6400000;                //    50,000
  float*          s2   = ws + 6450000;                //    50,000
  int*            cidx = (int*)(ws + 6500000);        //    50,000
  int*            isum = (int*)(ws + 6550000);        //         1
  int*            eidx = (int*)(ws + 6550004);        //   500,000
  unsigned short* Wb   = (unsigned short*)(ws + 7050004); // 32,768 bf16

  hipMemsetAsync(cidx, 0, (size_t)50001 * sizeof(int), stream);

  wconv_kernel<<<(IN_DIM * OUT_DIM) / 256, 256, 0, stream>>>(fc_w, Wb);
  gemm_mfma_kernel<<<(N_NODES + 63) / 64, 256, 0, stream>>>(h, Wb, attn, z, s1, s2);
  mean_hist_kernel<<<256, 256, 0, stream>>>(dist, dst, isum, cidx);
  scan_kernel<<<1, 1024, 0, stream>>>(cidx);
  fill_kernel<<<(N_EDGES + 255) / 256, 256, 0, stream>>>(dst, cidx, eidx);
  node_kernel<<<(N_NODES + 3) / 4, 256, 0, stream>>>(
      s1, s2, src, dist, isum, cidx, eidx, z, out);
}

// Round 11
// 175.892 us; speedup vs baseline: 3.5476x; 1.3890x over previous
//
#include <hip/hip_runtime.h>
#include <math.h>

#define N_NODES 50000
#define N_EDGES 500000
#define IN_DIM 256
#define OUT_DIM 128
#define NEG_SLOPE 0.01f
#define NB_SCAN 196  // ceil(50000/256)

typedef __attribute__((ext_vector_type(8))) short short8;
typedef __attribute__((ext_vector_type(4))) float f32x4;

// fp32 -> bf16 bits, round-to-nearest-even
__device__ __forceinline__ unsigned short f2bf(float f) {
  unsigned u = __float_as_uint(f);
  unsigned r = (u + 0x7FFFu + ((u >> 16) & 1u)) >> 16;
  return (unsigned short)r;
}

// ---------------- W fp32 -> bf16 (32768 elements, one-shot) ----------------
__global__ __launch_bounds__(256) void wconv_kernel(
    const float* __restrict__ W, unsigned short* __restrict__ Wb) {
  int i = blockIdx.x * 256 + threadIdx.x;
  Wb[i] = f2bf(W[i]);
}

// ---------------- MFMA GEMM: z = h @ W^T, fused s1/s2 epilogue ----------------
// No LDS, no barriers. Wave w of each block owns rows row0..row0+15; the wave
// computes all 128 cols as 8 col-tiles of 16x16x32 MFMAs over K=256.
// C/D: lane l, reg q -> row=(l>>4)*4+q, col=l&15   [m89-verified]
__global__ __launch_bounds__(256) void gemm_mfma_kernel(
    const float* __restrict__ h, const unsigned short* __restrict__ Wb,
    const float* __restrict__ aw,
    float* __restrict__ z, float* __restrict__ s1, float* __restrict__ s2) {
  const int wid  = threadIdx.x >> 6;
  const int lane = threadIdx.x & 63;
  const int row0 = blockIdx.x * 64 + wid * 16;
  const int r16  = lane & 15;
  const int kg   = lane >> 4;

  f32x4 acc[8];
#pragma unroll
  for (int ct = 0; ct < 8; ++ct) acc[ct] = (f32x4)(0.f);

  const int arow = row0 + r16;
  const size_t hbase = (size_t)((arow < N_NODES) ? arow : (N_NODES - 1)) * IN_DIM;

#pragma unroll 2
  for (int ks = 0; ks < 8; ++ks) {
    const int k0 = ks * 32 + kg * 8;
    const float4 a0 = *(const float4*)&h[hbase + k0];
    const float4 a1 = *(const float4*)&h[hbase + k0 + 4];
    short8 af;
    af[0] = (short)f2bf(a0.x); af[1] = (short)f2bf(a0.y);
    af[2] = (short)f2bf(a0.z); af[3] = (short)f2bf(a0.w);
    af[4] = (short)f2bf(a1.x); af[5] = (short)f2bf(a1.y);
    af[6] = (short)f2bf(a1.z); af[7] = (short)f2bf(a1.w);
#pragma unroll
    for (int ct = 0; ct < 8; ++ct) {
      const short8 bf = *(const short8*)&Wb[(size_t)(ct * 16 + r16) * IN_DIM + k0];
      acc[ct] = __builtin_amdgcn_mfma_f32_16x16x32_bf16(af, bf, acc[ct], 0, 0, 0);
    }
  }

#pragma unroll
  for (int q = 0; q < 4; ++q) {
    const int zr = row0 + kg * 4 + q;
    if (zr < N_NODES) {
#pragma unroll
      for (int ct = 0; ct < 8; ++ct)
        z[(size_t)zr * OUT_DIM + ct * 16 + r16] = acc[ct][q];
    }
  }

  float p1[4] = {0.f, 0.f, 0.f, 0.f}, p2[4] = {0.f, 0.f, 0.f, 0.f};
#pragma unroll
  for (int ct = 0; ct < 8; ++ct) {
    const float w1 = aw[ct * 16 + r16];
    const float w2 = aw[128 + ct * 16 + r16];
#pragma unroll
    for (int q = 0; q < 4; ++q) {
      p1[q] += acc[ct][q] * w1;
      p2[q] += acc[ct][q] * w2;
    }
  }
#pragma unroll
  for (int off = 8; off; off >>= 1) {
#pragma unroll
    for (int q = 0; q < 4; ++q) {
      p1[q] += __shfl_xor(p1[q], off);
      p2[q] += __shfl_xor(p2[q], off);
    }
  }
  if (r16 == 0) {
#pragma unroll
    for (int q = 0; q < 4; ++q) {
      const int zr = row0 + kg * 4 + q;
      if (zr < N_NODES) { s1[zr] = p1[q]; s2[zr] = p2[q]; }
    }
  }
}

// ---------------- fused: exact integer mean of dist + dst histogram ----------------
__global__ __launch_bounds__(256) void mean_hist_kernel(
    const int* __restrict__ dist, const int* __restrict__ dst,
    int* __restrict__ isum, int* __restrict__ cidx) {
  int tid = blockIdx.x * blockDim.x + threadIdx.x;
  int stride = gridDim.x * blockDim.x;
  int acc = 0;
  for (int i = tid; i < N_EDGES; i += stride) {
    acc += dist[i];
    atomicAdd(&cidx[dst[i]], 1);
  }
#pragma unroll
  for (int off = 32; off; off >>= 1) acc += __shfl_down(acc, off);
  if ((threadIdx.x & 63) == 0) atomicAdd(isum, acc);
}

// ---------------- hierarchical scan: A) per-block excl scan + totals ----------------
__global__ __launch_bounds__(256) void scanA_kernel(
    int* __restrict__ c, int* __restrict__ bsum) {
  __shared__ int tmp[256];
  const int t = threadIdx.x;
  const int i = blockIdx.x * 256 + t;
  const int v = (i < N_NODES) ? c[i] : 0;
  tmp[t] = v;
  __syncthreads();
#pragma unroll
  for (int off = 1; off < 256; off <<= 1) {
    int u = (t >= off) ? tmp[t - off] : 0;
    __syncthreads();
    tmp[t] += u;
    __syncthreads();
  }
  if (i < N_NODES) c[i] = tmp[t] - v;          // exclusive within block
  if (t == 255) bsum[blockIdx.x] = tmp[255];   // block total
}

// ---------------- B) scan the 196 block totals (one block) ----------------
__global__ __launch_bounds__(256) void scanB_kernel(int* __restrict__ bsum) {
  __shared__ int tmp[256];
  const int t = threadIdx.x;
  const int v = (t < NB_SCAN) ? bsum[t] : 0;
  tmp[t] = v;
  __syncthreads();
#pragma unroll
  for (int off = 1; off < 256; off <<= 1) {
    int u = (t >= off) ? tmp[t - off] : 0;
    __syncthreads();
    tmp[t] += u;
    __syncthreads();
  }
  if (t < NB_SCAN) bsum[t] = tmp[t] - v;       // exclusive block offsets
}

// ---------------- C) add block offsets ----------------
__global__ __launch_bounds__(256) void scanC_kernel(
    int* __restrict__ c, const int* __restrict__ bsum) {
  const int i = blockIdx.x * 256 + threadIdx.x;
  if (i < N_NODES) c[i] += bsum[blockIdx.x];
}

// ---------------- fill: CSR edge-id list (cursor advances starts -> ends) ----------------
__global__ __launch_bounds__(256) void fill_kernel(
    const int* __restrict__ dst, int* __restrict__ cursor,
    int* __restrict__ eidx) {
  int i = blockIdx.x * blockDim.x + threadIdx.x;
  if (i >= N_EDGES) return;
  int pos = atomicAdd(&cursor[dst[i]], 1);
  eidx[pos] = i;
}

// ---------------- node kernel: one wave per dst node ----------------
__global__ __launch_bounds__(256) void node_kernel(
    const float* __restrict__ s1, const float* __restrict__ s2,
    const int* __restrict__ src, const int* __restrict__ dist,
    const int* __restrict__ isum, const int* __restrict__ cidx,
    const int* __restrict__ eidx, const float* __restrict__ z,
    float* __restrict__ out) {
  const int wid = threadIdx.x >> 6, lane = threadIdx.x & 63;
  const int n = blockIdx.x * 4 + wid;
  if (n >= N_NODES) return;
  const int beg = (n == 0) ? 0 : cidx[n - 1];
  const int end = cidx[n];
  const int deg = end - beg;

  float2 acc = make_float2(0.f, 0.f);
  if (deg > 0) {
    const float mu = (float)(*isum) * (1.0f / N_EDGES);
    const float logmu = logf(mu);
    const float s2n = s2[n];

    if (deg <= 128) {
      float e0 = -INFINITY, e1 = -INFINITY;
      int src0r = 0, src1r = 0;
#pragma unroll
      for (int half = 0; half < 2; ++half) {
        int j = lane + half * 64;
        if (j < deg) {
          int idx = eidx[beg + j];
          float df = (float)dist[idx];
          float k = floorf(df * 0.5f);
          float p = expf(k * logmu - mu - lgammaf(k + 1.0f));
          int sn = src[idx];
          float a = s1[sn] + s2n;
          float lr = (a >= 0.f) ? a : NEG_SLOPE * a;
          float ev = p * lr;
          if (half == 0) { e0 = ev; src0r = sn; }
          else           { e1 = ev; src1r = sn; }
        }
      }
      float m = fmaxf(e0, e1);
#pragma unroll
      for (int off = 32; off; off >>= 1) m = fmaxf(m, __shfl_xor(m, off));
      float ex0 = expf(e0 - m), ex1 = expf(e1 - m);
      float ssum = ex0 + ex1;
#pragma unroll
      for (int off = 32; off; off >>= 1) ssum += __shfl_xor(ssum, off);
      const float inv = 1.0f / ssum;
      const float a0 = ex0 * inv, a1 = ex1 * inv;
      for (int jj = 0; jj < deg; ++jj) {
        float alpha = __shfl((jj < 64) ? a0 : a1, jj & 63);
        int   sidx  = __shfl((jj < 64) ? src0r : src1r, jj & 63);
        const float2 zv = *(const float2*)&z[(size_t)sidx * OUT_DIM + lane * 2];
        acc.x += alpha * zv.x;
        acc.y += alpha * zv.y;
      }
    } else {
      float m = -INFINITY;
      for (int j = lane; j < deg; j += 64) {
        int idx = eidx[beg + j];
        float df = (float)dist[idx];
        float k = floorf(df * 0.5f);
        float p = expf(k * logmu - mu - lgammaf(k + 1.0f));
        float a = s1[src[idx]] + s2n;
        float ev = p * ((a >= 0.f) ? a : NEG_SLOPE * a);
        m = fmaxf(m, ev);
      }
#pragma unroll
      for (int off = 32; off; off >>= 1) m = fmaxf(m, __shfl_xor(m, off));
      float ssum = 0.f;
      for (int j = lane; j < deg; j += 64) {
        int idx = eidx[beg + j];
        float df = (float)dist[idx];
        float k = floorf(df * 0.5f);
        float p = expf(k * logmu - mu - lgammaf(k + 1.0f));
        float a = s1[src[idx]] + s2n;
        float ev = p * ((a >= 0.f) ? a : NEG_SLOPE * a);
        ssum += expf(ev - m);
      }
#pragma unroll
      for (int off = 32; off; off >>= 1) ssum += __shfl_xor(ssum, off);
      const float inv = 1.0f / ssum;
      for (int jj = 0; jj < deg; ++jj) {
        int idx = eidx[beg + jj];
        float df = (float)dist[idx];
        float k = floorf(df * 0.5f);
        float p = expf(k * logmu - mu - lgammaf(k + 1.0f));
        int sidx = src[idx];
        float a = s1[sidx] + s2n;
        float ev = p * ((a >= 0.f) ? a : NEG_SLOPE * a);
        float alpha = expf(ev - m) * inv;
        const float2 zv = *(const float2*)&z[(size_t)sidx * OUT_DIM + lane * 2];
        acc.x += alpha * zv.x;
        acc.y += alpha * zv.y;
      }
    }
  }
  *(float2*)&out[(size_t)n * OUT_DIM + lane * 2] = acc;
}

extern "C" void kernel_launch(void* const* d_in, const int* in_sizes, int n_in,
                              void* d_out, int out_size, void* d_ws, size_t ws_size,
                              hipStream_t stream) {
  const float* h    = (const float*)d_in[0];
  const float* fc_w = (const float*)d_in[1];
  const float* attn = (const float*)d_in[2];
  const int*   src  = (const int*)d_in[3];
  const int*   dst  = (const int*)d_in[4];
  const int*   dist = (const int*)d_in[5];
  float* out = (float*)d_out;
  float* ws  = (float*)d_ws;

  // workspace layout (4-byte units), total 7,066,584 * 4B = 28.27 MB
  float*          z    = ws;                          // 6,400,000 floats
  float*          s1   = ws + 6400000;                //    50,000
  float*          s2   = ws + 6450000;                //    50,000
  int*            cidx = (int*)(ws + 6500000);        //    50,000
  int*            isum = (int*)(ws + 6550000);        //         1
  int*            eidx = (int*)(ws + 6550004);        //   500,000
  unsigned short* Wb   = (unsigned short*)(ws + 7050004); // 32,768 bf16
  int*            bsum = (int*)(ws + 7066388);        //       196

  hipMemsetAsync(cidx, 0, (size_t)50001 * sizeof(int), stream);

  wconv_kernel<<<(IN_DIM * OUT_DIM) / 256, 256, 0, stream>>>(fc_w, Wb);
  gemm_mfma_kernel<<<(N_NODES + 63) / 64, 256, 0, stream>>>(h, Wb, attn, z, s1, s2);
  mean_hist_kernel<<<256, 256, 0, stream>>>(dist, dst, isum, cidx);
  scanA_kernel<<<NB_SCAN, 256, 0, stream>>>(cidx, bsum);
  scanB_kernel<<<1, 256, 0, stream>>>(bsum);
  scanC_kernel<<<NB_SCAN, 256, 0, stream>>>(cidx, bsum);
  fill_kernel<<<(N_EDGES + 255) / 256, 256, 0, stream>>>(dst, cidx, eidx);
  node_kernel<<<(N_NODES + 3) / 4, 256, 0, stream>>>(
      s1, s2, src, dist, isum, cidx, eidx, z, out);
}

// Round 12
// 169.232 us; speedup vs baseline: 3.6872x; 1.0394x over previous
//
#include <hip/hip_runtime.h>
#include <math.h>

#define N_NODES 50000
#define N_EDGES 500000
#define IN_DIM 256
#define OUT_DIM 128
#define NEG_SLOPE 0.01f
#define NB_SCAN 196  // ceil(50000/256)

typedef __attribute__((ext_vector_type(8))) short short8;
typedef __attribute__((ext_vector_type(4))) float f32x4;

// fp32 -> bf16 bits, round-to-nearest-even
__device__ __forceinline__ unsigned short f2bf(float f) {
  unsigned u = __float_as_uint(f);
  unsigned r = (u + 0x7FFFu + ((u >> 16) & 1u)) >> 16;
  return (unsigned short)r;
}

// ---------------- W fp32 -> bf16 (32768 elements, one-shot) ----------------
__global__ __launch_bounds__(256) void wconv_kernel(
    const float* __restrict__ W, unsigned short* __restrict__ Wb) {
  int i = blockIdx.x * 256 + threadIdx.x;
  Wb[i] = f2bf(W[i]);
}

// ---------------- MFMA GEMM: z = h @ W^T (z stored bf16), fused s1/s2 ----------------
// No LDS, no barriers. Wave w owns rows row0..row0+15, all 128 cols, K=256.
// C/D: lane l, reg q -> row=(l>>4)*4+q, col=l&15   [m89-verified]
__global__ __launch_bounds__(256) void gemm_mfma_kernel(
    const float* __restrict__ h, const unsigned short* __restrict__ Wb,
    const float* __restrict__ aw,
    unsigned short* __restrict__ zb, float* __restrict__ s1, float* __restrict__ s2) {
  const int wid  = threadIdx.x >> 6;
  const int lane = threadIdx.x & 63;
  const int row0 = blockIdx.x * 64 + wid * 16;
  const int r16  = lane & 15;
  const int kg   = lane >> 4;

  f32x4 acc[8];
#pragma unroll
  for (int ct = 0; ct < 8; ++ct) acc[ct] = (f32x4)(0.f);

  const int arow = row0 + r16;
  const size_t hbase = (size_t)((arow < N_NODES) ? arow : (N_NODES - 1)) * IN_DIM;

#pragma unroll 2
  for (int ks = 0; ks < 8; ++ks) {
    const int k0 = ks * 32 + kg * 8;
    const float4 a0 = *(const float4*)&h[hbase + k0];
    const float4 a1 = *(const float4*)&h[hbase + k0 + 4];
    short8 af;
    af[0] = (short)f2bf(a0.x); af[1] = (short)f2bf(a0.y);
    af[2] = (short)f2bf(a0.z); af[3] = (short)f2bf(a0.w);
    af[4] = (short)f2bf(a1.x); af[5] = (short)f2bf(a1.y);
    af[6] = (short)f2bf(a1.z); af[7] = (short)f2bf(a1.w);
#pragma unroll
    for (int ct = 0; ct < 8; ++ct) {
      const short8 bf = *(const short8*)&Wb[(size_t)(ct * 16 + r16) * IN_DIM + k0];
      acc[ct] = __builtin_amdgcn_mfma_f32_16x16x32_bf16(af, bf, acc[ct], 0, 0, 0);
    }
  }

  // store z as bf16: lane l, reg q -> row row0+(l>>4)*4+q, col ct*16+(l&15)
#pragma unroll
  for (int q = 0; q < 4; ++q) {
    const int zr = row0 + kg * 4 + q;
    if (zr < N_NODES) {
#pragma unroll
      for (int ct = 0; ct < 8; ++ct)
        zb[(size_t)zr * OUT_DIM + ct * 16 + r16] = f2bf(acc[ct][q]);
    }
  }

  float p1[4] = {0.f, 0.f, 0.f, 0.f}, p2[4] = {0.f, 0.f, 0.f, 0.f};
#pragma unroll
  for (int ct = 0; ct < 8; ++ct) {
    const float w1 = aw[ct * 16 + r16];
    const float w2 = aw[128 + ct * 16 + r16];
#pragma unroll
    for (int q = 0; q < 4; ++q) {
      p1[q] += acc[ct][q] * w1;
      p2[q] += acc[ct][q] * w2;
    }
  }
#pragma unroll
  for (int off = 8; off; off >>= 1) {
#pragma unroll
    for (int q = 0; q < 4; ++q) {
      p1[q] += __shfl_xor(p1[q], off);
      p2[q] += __shfl_xor(p2[q], off);
    }
  }
  if (r16 == 0) {
#pragma unroll
    for (int q = 0; q < 4; ++q) {
      const int zr = row0 + kg * 4 + q;
      if (zr < N_NODES) { s1[zr] = p1[q]; s2[zr] = p2[q]; }
    }
  }
}

// ---------------- fused: exact integer mean of dist + dst histogram ----------------
__global__ __launch_bounds__(256) void mean_hist_kernel(
    const int* __restrict__ dist, const int* __restrict__ dst,
    int* __restrict__ isum, int* __restrict__ cidx) {
  int tid = blockIdx.x * blockDim.x + threadIdx.x;
  int stride = gridDim.x * blockDim.x;
  int acc = 0;
  for (int i = tid; i < N_EDGES; i += stride) {
    acc += dist[i];
    atomicAdd(&cidx[dst[i]], 1);
  }
#pragma unroll
  for (int off = 32; off; off >>= 1) acc += __shfl_down(acc, off);
  if ((threadIdx.x & 63) == 0) atomicAdd(isum, acc);
}

// ---------------- hierarchical scan: A) per-block excl scan + totals ----------------
__global__ __launch_bounds__(256) void scanA_kernel(
    int* __restrict__ c, int* __restrict__ bsum) {
  __shared__ int tmp[256];
  const int t = threadIdx.x;
  const int i = blockIdx.x * 256 + t;
  const int v = (i < N_NODES) ? c[i] : 0;
  tmp[t] = v;
  __syncthreads();
#pragma unroll
  for (int off = 1; off < 256; off <<= 1) {
    int u = (t >= off) ? tmp[t - off] : 0;
    __syncthreads();
    tmp[t] += u;
    __syncthreads();
  }
  if (i < N_NODES) c[i] = tmp[t] - v;          // exclusive within block
  if (t == 255) bsum[blockIdx.x] = tmp[255];   // block total
}

// ---------------- B) scan the 196 block totals (one block) ----------------
__global__ __launch_bounds__(256) void scanB_kernel(int* __restrict__ bsum) {
  __shared__ int tmp[256];
  const int t = threadIdx.x;
  const int v = (t < NB_SCAN) ? bsum[t] : 0;
  tmp[t] = v;
  __syncthreads();
#pragma unroll
  for (int off = 1; off < 256; off <<= 1) {
    int u = (t >= off) ? tmp[t - off] : 0;
    __syncthreads();
    tmp[t] += u;
    __syncthreads();
  }
  if (t < NB_SCAN) bsum[t] = tmp[t] - v;       // exclusive block offsets
}

// ---------------- C) add block offsets ----------------
__global__ __launch_bounds__(256) void scanC_kernel(
    int* __restrict__ c, const int* __restrict__ bsum) {
  const int i = blockIdx.x * 256 + threadIdx.x;
  if (i < N_NODES) c[i] += bsum[blockIdx.x];
}

// ---------------- fill: CSR edge-id list (cursor advances starts -> ends) ----------------
__global__ __launch_bounds__(256) void fill_kernel(
    const int* __restrict__ dst, int* __restrict__ cursor,
    int* __restrict__ eidx) {
  int i = blockIdx.x * blockDim.x + threadIdx.x;
  if (i >= N_EDGES) return;
  int pos = atomicAdd(&cursor[dst[i]], 1);
  eidx[pos] = i;
}

// ---------------- node kernel: one wave per dst node (bf16 z gather) ----------------
__global__ __launch_bounds__(256) void node_kernel(
    const float* __restrict__ s1, const float* __restrict__ s2,
    const int* __restrict__ src, const int* __restrict__ dist,
    const int* __restrict__ isum, const int* __restrict__ cidx,
    const int* __restrict__ eidx, const unsigned* __restrict__ zbu,
    float* __restrict__ out) {
  const int wid = threadIdx.x >> 6, lane = threadIdx.x & 63;
  const int n = blockIdx.x * 4 + wid;
  if (n >= N_NODES) return;
  const int beg = (n == 0) ? 0 : cidx[n - 1];
  const int end = cidx[n];
  const int deg = end - beg;

  float2 acc = make_float2(0.f, 0.f);
  if (deg > 0) {
    const float mu = (float)(*isum) * (1.0f / N_EDGES);
    const float logmu = logf(mu);
    const float s2n = s2[n];

    if (deg <= 128) {
      float e0 = -INFINITY, e1 = -INFINITY;
      int src0r = 0, src1r = 0;
#pragma unroll
      for (int half = 0; half < 2; ++half) {
        int j = lane + half * 64;
        if (j < deg) {
          int idx = eidx[beg + j];
          float df = (float)dist[idx];
          float k = floorf(df * 0.5f);
          float p = expf(k * logmu - mu - lgammaf(k + 1.0f));
          int sn = src[idx];
          float a = s1[sn] + s2n;
          float lr = (a >= 0.f) ? a : NEG_SLOPE * a;
          float ev = p * lr;
          if (half == 0) { e0 = ev; src0r = sn; }
          else           { e1 = ev; src1r = sn; }
        }
      }
      float m = fmaxf(e0, e1);
#pragma unroll
      for (int off = 32; off; off >>= 1) m = fmaxf(m, __shfl_xor(m, off));
      float ex0 = expf(e0 - m), ex1 = expf(e1 - m);
      float ssum = ex0 + ex1;
#pragma unroll
      for (int off = 32; off; off >>= 1) ssum += __shfl_xor(ssum, off);
      const float inv = 1.0f / ssum;
      const float a0 = ex0 * inv, a1 = ex1 * inv;
      for (int jj = 0; jj < deg; ++jj) {
        float alpha = __shfl((jj < 64) ? a0 : a1, jj & 63);
        int   sidx  = __shfl((jj < 64) ? src0r : src1r, jj & 63);
        const unsigned v = zbu[(size_t)sidx * 64 + lane];
        acc.x += alpha * __uint_as_float((v & 0xFFFFu) << 16);
        acc.y += alpha * __uint_as_float(v & 0xFFFF0000u);
      }
    } else {
      float m = -INFINITY;
      for (int j = lane; j < deg; j += 64) {
        int idx = eidx[beg + j];
        float df = (float)dist[idx];
        float k = floorf(df * 0.5f);
        float p = expf(k * logmu - mu - lgammaf(k + 1.0f));
        float a = s1[src[idx]] + s2n;
        float ev = p * ((a >= 0.f) ? a : NEG_SLOPE * a);
        m = fmaxf(m, ev);
      }
#pragma unroll
      for (int off = 32; off; off >>= 1) m = fmaxf(m, __shfl_xor(m, off));
      float ssum = 0.f;
      for (int j = lane; j < deg; j += 64) {
        int idx = eidx[beg + j];
        float df = (float)dist[idx];
        float k = floorf(df * 0.5f);
        float p = expf(k * logmu - mu - lgammaf(k + 1.0f));
        float a = s1[src[idx]] + s2n;
        float ev = p * ((a >= 0.f) ? a : NEG_SLOPE * a);
        ssum += expf(ev - m);
      }
#pragma unroll
      for (int off = 32; off; off >>= 1) ssum += __shfl_xor(ssum, off);
      const float inv = 1.0f / ssum;
      for (int jj = 0; jj < deg; ++jj) {
        int idx = eidx[beg + jj];
        float df = (float)dist[idx];
        float k = floorf(df * 0.5f);
        float p = expf(k * logmu - mu - lgammaf(k + 1.0f));
        int sidx = src[idx];
        float a = s1[sidx] + s2n;
        float ev = p * ((a >= 0.f) ? a : NEG_SLOPE * a);
        float alpha = expf(ev - m) * inv;
        const unsigned v = zbu[(size_t)sidx * 64 + lane];
        acc.x += alpha * __uint_as_float((v & 0xFFFFu) << 16);
        acc.y += alpha * __uint_as_float(v & 0xFFFF0000u);
      }
    }
  }
  *(float2*)&out[(size_t)n * OUT_DIM + lane * 2] = acc;
}

extern "C" void kernel_launch(void* const* d_in, const int* in_sizes, int n_in,
                              void* d_out, int out_size, void* d_ws, size_t ws_size,
                              hipStream_t stream) {
  const float* h    = (const float*)d_in[0];
  const float* fc_w = (const float*)d_in[1];
  const float* attn = (const float*)d_in[2];
  const int*   src  = (const int*)d_in[3];
  const int*   dst  = (const int*)d_in[4];
  const int*   dist = (const int*)d_in[5];
  float* out = (float*)d_out;
  float* ws  = (float*)d_ws;

  // workspace layout (4-byte units) — z region now bf16 (uses half), offsets kept
  unsigned short* zb   = (unsigned short*)ws;         // 6,400,000 bf16 (3.2M words)
  float*          s1   = ws + 6400000;                //    50,000
  float*          s2   = ws + 6450000;                //    50,000
  int*            cidx = (int*)(ws + 6500000);        //    50,000
  int*            isum = (int*)(ws + 6550000);        //         1
  int*            eidx = (int*)(ws + 6550004);        //   500,000
  unsigned short* Wb   = (unsigned short*)(ws + 7050004); // 32,768 bf16
  int*            bsum = (int*)(ws + 7066388);        //       196

  hipMemsetAsync(cidx, 0, (size_t)50001 * sizeof(int), stream);

  wconv_kernel<<<(IN_DIM * OUT_DIM) / 256, 256, 0, stream>>>(fc_w, Wb);
  gemm_mfma_kernel<<<(N_NODES + 63) / 64, 256, 0, stream>>>(h, Wb, attn, zb, s1, s2);
  mean_hist_kernel<<<256, 256, 0, stream>>>(dist, dst, isum, cidx);
  scanA_kernel<<<NB_SCAN, 256, 0, stream>>>(cidx, bsum);
  scanB_kernel<<<1, 256, 0, stream>>>(bsum);
  scanC_kernel<<<NB_SCAN, 256, 0, stream>>>(cidx, bsum);
  fill_kernel<<<(N_EDGES + 255) / 256, 256, 0, stream>>>(dst, cidx, eidx);
  node_kernel<<<(N_NODES + 3) / 4, 256, 0, stream>>>(
      s1, s2, src, dist, isum, cidx, eidx, (const unsigned*)zb, out);
}

// Round 13
// 167.977 us; speedup vs baseline: 3.7148x; 1.0075x over previous
//
#include <hip/hip_runtime.h>
#include <math.h>

#define N_NODES 50000
#define N_EDGES 500000
#define IN_DIM 256
#define OUT_DIM 128
#define NEG_SLOPE 0.01f
#define NB_SCAN 196  // ceil(50000/256)

typedef __attribute__((ext_vector_type(8))) short short8;
typedef __attribute__((ext_vector_type(4))) float f32x4;

// fp32 -> bf16 bits, round-to-nearest-even
__device__ __forceinline__ unsigned short f2bf(float f) {
  unsigned u = __float_as_uint(f);
  unsigned r = (u + 0x7FFFu + ((u >> 16) & 1u)) >> 16;
  return (unsigned short)r;
}

// ---------------- W fp32 -> bf16 (32768 elements, one-shot) ----------------
__global__ __launch_bounds__(256) void wconv_kernel(
    const float* __restrict__ W, unsigned short* __restrict__ Wb) {
  int i = blockIdx.x * 256 + threadIdx.x;
  Wb[i] = f2bf(W[i]);
}

// ---------------- MFMA GEMM: z = h @ W^T (z stored bf16), fused s1/s2 ----------------
// C/D: lane l, reg q -> row=(l>>4)*4+q, col=l&15   [m89-verified]
__global__ __launch_bounds__(256) void gemm_mfma_kernel(
    const float* __restrict__ h, const unsigned short* __restrict__ Wb,
    const float* __restrict__ aw,
    unsigned short* __restrict__ zb, float* __restrict__ s1, float* __restrict__ s2) {
  const int wid  = threadIdx.x >> 6;
  const int lane = threadIdx.x & 63;
  const int row0 = blockIdx.x * 64 + wid * 16;
  const int r16  = lane & 15;
  const int kg   = lane >> 4;

  f32x4 acc[8];
#pragma unroll
  for (int ct = 0; ct < 8; ++ct) acc[ct] = (f32x4)(0.f);

  const int arow = row0 + r16;
  const size_t hbase = (size_t)((arow < N_NODES) ? arow : (N_NODES - 1)) * IN_DIM;

#pragma unroll 2
  for (int ks = 0; ks < 8; ++ks) {
    const int k0 = ks * 32 + kg * 8;
    const float4 a0 = *(const float4*)&h[hbase + k0];
    const float4 a1 = *(const float4*)&h[hbase + k0 + 4];
    short8 af;
    af[0] = (short)f2bf(a0.x); af[1] = (short)f2bf(a0.y);
    af[2] = (short)f2bf(a0.z); af[3] = (short)f2bf(a0.w);
    af[4] = (short)f2bf(a1.x); af[5] = (short)f2bf(a1.y);
    af[6] = (short)f2bf(a1.z); af[7] = (short)f2bf(a1.w);
#pragma unroll
    for (int ct = 0; ct < 8; ++ct) {
      const short8 bf = *(const short8*)&Wb[(size_t)(ct * 16 + r16) * IN_DIM + k0];
      acc[ct] = __builtin_amdgcn_mfma_f32_16x16x32_bf16(af, bf, acc[ct], 0, 0, 0);
    }
  }

#pragma unroll
  for (int q = 0; q < 4; ++q) {
    const int zr = row0 + kg * 4 + q;
    if (zr < N_NODES) {
#pragma unroll
      for (int ct = 0; ct < 8; ++ct)
        zb[(size_t)zr * OUT_DIM + ct * 16 + r16] = f2bf(acc[ct][q]);
    }
  }

  float p1[4] = {0.f, 0.f, 0.f, 0.f}, p2[4] = {0.f, 0.f, 0.f, 0.f};
#pragma unroll
  for (int ct = 0; ct < 8; ++ct) {
    const float w1 = aw[ct * 16 + r16];
    const float w2 = aw[128 + ct * 16 + r16];
#pragma unroll
    for (int q = 0; q < 4; ++q) {
      p1[q] += acc[ct][q] * w1;
      p2[q] += acc[ct][q] * w2;
    }
  }
#pragma unroll
  for (int off = 8; off; off >>= 1) {
#pragma unroll
    for (int q = 0; q < 4; ++q) {
      p1[q] += __shfl_xor(p1[q], off);
      p2[q] += __shfl_xor(p2[q], off);
    }
  }
  if (r16 == 0) {
#pragma unroll
    for (int q = 0; q < 4; ++q) {
      const int zr = row0 + kg * 4 + q;
      if (zr < N_NODES) { s1[zr] = p1[q]; s2[zr] = p2[q]; }
    }
  }
}

// ---------------- fused: exact integer mean of dist + dst histogram ----------------
__global__ __launch_bounds__(256) void mean_hist_kernel(
    const int* __restrict__ dist, const int* __restrict__ dst,
    int* __restrict__ isum, int* __restrict__ cidx) {
  int tid = blockIdx.x * blockDim.x + threadIdx.x;
  int stride = gridDim.x * blockDim.x;
  int acc = 0;
  for (int i = tid; i < N_EDGES; i += stride) {
    acc += dist[i];
    atomicAdd(&cidx[dst[i]], 1);
  }
#pragma unroll
  for (int off = 32; off; off >>= 1) acc += __shfl_down(acc, off);
  if ((threadIdx.x & 63) == 0) atomicAdd(isum, acc);
}

// ---------------- pmf lookup table: lut[d] = poisson_pmf(d>>1, mu), d in [0,100) ----------------
__global__ __launch_bounds__(128) void lut_kernel(
    const int* __restrict__ isum, float* __restrict__ lut) {
  const int d = threadIdx.x;
  if (d >= 100) return;
  const float mu = (float)(*isum) * (1.0f / N_EDGES);
  const float k = (float)(d >> 1);
  lut[d] = expf(k * logf(mu) - mu - lgammaf(k + 1.0f));
}

// ---------------- hierarchical scan: A) per-block excl scan + totals ----------------
__global__ __launch_bounds__(256) void scanA_kernel(
    int* __restrict__ c, int* __restrict__ bsum) {
  __shared__ int tmp[256];
  const int t = threadIdx.x;
  const int i = blockIdx.x * 256 + t;
  const int v = (i < N_NODES) ? c[i] : 0;
  tmp[t] = v;
  __syncthreads();
#pragma unroll
  for (int off = 1; off < 256; off <<= 1) {
    int u = (t >= off) ? tmp[t - off] : 0;
    __syncthreads();
    tmp[t] += u;
    __syncthreads();
  }
  if (i < N_NODES) c[i] = tmp[t] - v;          // exclusive within block
  if (t == 255) bsum[blockIdx.x] = tmp[255];   // block total
}

// ---------------- B) scan the 196 block totals (one block) ----------------
__global__ __launch_bounds__(256) void scanB_kernel(int* __restrict__ bsum) {
  __shared__ int tmp[256];
  const int t = threadIdx.x;
  const int v = (t < NB_SCAN) ? bsum[t] : 0;
  tmp[t] = v;
  __syncthreads();
#pragma unroll
  for (int off = 1; off < 256; off <<= 1) {
    int u = (t >= off) ? tmp[t - off] : 0;
    __syncthreads();
    tmp[t] += u;
    __syncthreads();
  }
  if (t < NB_SCAN) bsum[t] = tmp[t] - v;       // exclusive block offsets
}

// ---------------- C) add block offsets ----------------
__global__ __launch_bounds__(256) void scanC_kernel(
    int* __restrict__ c, const int* __restrict__ bsum) {
  const int i = blockIdx.x * 256 + threadIdx.x;
  if (i < N_NODES) c[i] += bsum[blockIdx.x];
}

// ---------------- fill: CSR-ordered (src, e) per edge; e fully scored here ----------------
// e = lut[dist] * leaky_relu(s1[src] + s2[dst]); all 64 lanes active.
__global__ __launch_bounds__(256) void fill_kernel(
    const int* __restrict__ dst, const int* __restrict__ src,
    const int* __restrict__ dist,
    const float* __restrict__ s1, const float* __restrict__ s2,
    const float* __restrict__ lut,
    int* __restrict__ cursor, int* __restrict__ esrc, float* __restrict__ ee) {
  int i = blockIdx.x * blockDim.x + threadIdx.x;
  if (i >= N_EDGES) return;
  const int d = dst[i];
  const int s = src[i];
  const float p = lut[dist[i]];
  const float a = s1[s] + s2[d];
  const float ev = p * ((a >= 0.f) ? a : NEG_SLOPE * a);
  const int pos = atomicAdd(&cursor[d], 1);
  esrc[pos] = s;
  ee[pos] = ev;
}

// ---------------- node kernel: one wave per dst node ----------------
// Softmax from contiguous ee[beg..end); walk with uniform broadcast loads
// (no shuffles in the dependent chain) + unroll-4 overlapped row gathers.
__global__ __launch_bounds__(256) void node_kernel(
    const int* __restrict__ cidx, const int* __restrict__ esrc,
    const float* __restrict__ ee, const unsigned* __restrict__ zbu,
    float* __restrict__ out) {
  const int wid = threadIdx.x >> 6, lane = threadIdx.x & 63;
  const int n = blockIdx.x * 4 + wid;
  if (n >= N_NODES) return;
  const int beg = (n == 0) ? 0 : cidx[n - 1];
  const int end = cidx[n];
  const int deg = end - beg;

  float2 acc = make_float2(0.f, 0.f);
  if (deg > 0) {
    float m, ssum;
    if (deg <= 64) {
      float e0 = (lane < deg) ? ee[beg + lane] : -INFINITY;
      m = e0;
#pragma unroll
      for (int off = 32; off; off >>= 1) m = fmaxf(m, __shfl_xor(m, off));
      ssum = expf(e0 - m);   // 0 for invalid lanes
#pragma unroll
      for (int off = 32; off; off >>= 1) ssum += __shfl_xor(ssum, off);
    } else {
      float mm = -INFINITY;
      for (int j = lane; j < deg; j += 64) mm = fmaxf(mm, ee[beg + j]);
      m = mm;
#pragma unroll
      for (int off = 32; off; off >>= 1) m = fmaxf(m, __shfl_xor(m, off));
      float ss = 0.f;
      for (int j = lane; j < deg; j += 64) ss += expf(ee[beg + j] - m);
      ssum = ss;
#pragma unroll
      for (int off = 32; off; off >>= 1) ssum += __shfl_xor(ssum, off);
    }
    const float inv = 1.0f / ssum;

    // walk: per edge, wave-uniform alpha (broadcast load + exp) and row gather
#pragma unroll 4
    for (int jj = 0; jj < deg; ++jj) {
      const float al = expf(ee[beg + jj] - m) * inv;
      const int   sj = esrc[beg + jj];
      const unsigned v = zbu[(size_t)sj * 64 + lane];
      acc.x += al * __uint_as_float((v & 0xFFFFu) << 16);
      acc.y += al * __uint_as_float(v & 0xFFFF0000u);
    }
  }
  *(float2*)&out[(size_t)n * OUT_DIM + lane * 2] = acc;
}

extern "C" void kernel_launch(void* const* d_in, const int* in_sizes, int n_in,
                              void* d_out, int out_size, void* d_ws, size_t ws_size,
                              hipStream_t stream) {
  const float* h    = (const float*)d_in[0];
  const float* fc_w = (const float*)d_in[1];
  const float* attn = (const float*)d_in[2];
  const int*   src  = (const int*)d_in[3];
  const int*   dst  = (const int*)d_in[4];
  const int*   dist = (const int*)d_in[5];
  float* out = (float*)d_out;
  float* ws  = (float*)d_ws;

  // workspace layout (4-byte units), total ~4.37M words = 17.5 MB
  unsigned short* zb   = (unsigned short*)ws;         // 6,400,000 bf16 = 3,200,000 words
  float*          s1   = ws + 3200000;                //    50,000
  float*          s2   = ws + 3250000;                //    50,000
  int*            cidx = (int*)(ws + 3300000);        //    50,000
  int*            isum = (int*)(ws + 3350000);        //         1 (contiguous after cidx)
  float*          lut  = ws + 3350004;                //       100
  int*            esrc = (int*)(ws + 3350104);        //   500,000
  float*          ee   = ws + 3850104;                //   500,000
  unsigned short* Wb   = (unsigned short*)(ws + 4350104); // 32,768 bf16 = 16,384 words
  int*            bsum = (int*)(ws + 4366488);        //       196

  hipMemsetAsync(cidx, 0, (size_t)50001 * sizeof(int), stream);

  wconv_kernel<<<(IN_DIM * OUT_DIM) / 256, 256, 0, stream>>>(fc_w, Wb);
  gemm_mfma_kernel<<<(N_NODES + 63) / 64, 256, 0, stream>>>(h, Wb, attn, zb, s1, s2);
  mean_hist_kernel<<<256, 256, 0, stream>>>(dist, dst, isum, cidx);
  lut_kernel<<<1, 128, 0, stream>>>(isum, lut);
  scanA_kernel<<<NB_SCAN, 256, 0, stream>>>(cidx, bsum);
  scanB_kernel<<<1, 256, 0, stream>>>(bsum);
  scanC_kernel<<<NB_SCAN, 256, 0, stream>>>(cidx, bsum);
  fill_kernel<<<(N_EDGES + 255) / 256, 256, 0, stream>>>(
      dst, src, dist, s1, s2, lut, cidx, esrc, ee);
  node_kernel<<<(N_NODES + 3) / 4, 256, 0, stream>>>(
      cidx, esrc, ee, (const unsigned*)zb, out);
}

// Round 14
// 138.257 us; speedup vs baseline: 4.5133x; 1.2150x over previous
//
#include <hip/hip_runtime.h>
#include <math.h>

#define N_NODES 50000
#define N_EDGES 500000
#define IN_DIM 256
#define OUT_DIM 128
#define NEG_SLOPE 0.01f
#define NB_SCAN 196  // ceil(50000/256)

typedef __attribute__((ext_vector_type(8))) short short8;
typedef __attribute__((ext_vector_type(4))) float f32x4;

// fp32 -> bf16 bits, round-to-nearest-even
__device__ __forceinline__ unsigned short f2bf(float f) {
  unsigned u = __float_as_uint(f);
  unsigned r = (u + 0x7FFFu + ((u >> 16) & 1u)) >> 16;
  return (unsigned short)r;
}

// ---------------- W fp32 -> bf16 (32768 elements, one-shot) ----------------
__global__ __launch_bounds__(256) void wconv_kernel(
    const float* __restrict__ W, unsigned short* __restrict__ Wb) {
  int i = blockIdx.x * 256 + threadIdx.x;
  Wb[i] = f2bf(W[i]);
}

// ---------------- MFMA GEMM: z = h @ W^T (z stored bf16), fused s1/s2 ----------------
// C/D: lane l, reg q -> row=(l>>4)*4+q, col=l&15   [m89-verified]
__global__ __launch_bounds__(256) void gemm_mfma_kernel(
    const float* __restrict__ h, const unsigned short* __restrict__ Wb,
    const float* __restrict__ aw,
    unsigned short* __restrict__ zb, float* __restrict__ s1, float* __restrict__ s2) {
  const int wid  = threadIdx.x >> 6;
  const int lane = threadIdx.x & 63;
  const int row0 = blockIdx.x * 64 + wid * 16;
  const int r16  = lane & 15;
  const int kg   = lane >> 4;

  f32x4 acc[8];
#pragma unroll
  for (int ct = 0; ct < 8; ++ct) acc[ct] = (f32x4)(0.f);

  const int arow = row0 + r16;
  const size_t hbase = (size_t)((arow < N_NODES) ? arow : (N_NODES - 1)) * IN_DIM;

#pragma unroll 2
  for (int ks = 0; ks < 8; ++ks) {
    const int k0 = ks * 32 + kg * 8;
    const float4 a0 = *(const float4*)&h[hbase + k0];
    const float4 a1 = *(const float4*)&h[hbase + k0 + 4];
    short8 af;
    af[0] = (short)f2bf(a0.x); af[1] = (short)f2bf(a0.y);
    af[2] = (short)f2bf(a0.z); af[3] = (short)f2bf(a0.w);
    af[4] = (short)f2bf(a1.x); af[5] = (short)f2bf(a1.y);
    af[6] = (short)f2bf(a1.z); af[7] = (short)f2bf(a1.w);
#pragma unroll
    for (int ct = 0; ct < 8; ++ct) {
      const short8 bf = *(const short8*)&Wb[(size_t)(ct * 16 + r16) * IN_DIM + k0];
      acc[ct] = __builtin_amdgcn_mfma_f32_16x16x32_bf16(af, bf, acc[ct], 0, 0, 0);
    }
  }

#pragma unroll
  for (int q = 0; q < 4; ++q) {
    const int zr = row0 + kg * 4 + q;
    if (zr < N_NODES) {
#pragma unroll
      for (int ct = 0; ct < 8; ++ct)
        zb[(size_t)zr * OUT_DIM + ct * 16 + r16] = f2bf(acc[ct][q]);
    }
  }

  float p1[4] = {0.f, 0.f, 0.f, 0.f}, p2[4] = {0.f, 0.f, 0.f, 0.f};
#pragma unroll
  for (int ct = 0; ct < 8; ++ct) {
    const float w1 = aw[ct * 16 + r16];
    const float w2 = aw[128 + ct * 16 + r16];
#pragma unroll
    for (int q = 0; q < 4; ++q) {
      p1[q] += acc[ct][q] * w1;
      p2[q] += acc[ct][q] * w2;
    }
  }
#pragma unroll
  for (int off = 8; off; off >>= 1) {
#pragma unroll
    for (int q = 0; q < 4; ++q) {
      p1[q] += __shfl_xor(p1[q], off);
      p2[q] += __shfl_xor(p2[q], off);
    }
  }
  if (r16 == 0) {
#pragma unroll
    for (int q = 0; q < 4; ++q) {
      const int zr = row0 + kg * 4 + q;
      if (zr < N_NODES) { s1[zr] = p1[q]; s2[zr] = p2[q]; }
    }
  }
}

// ---------------- fused: dist mean + dst histogram + RANK capture ----------------
// The histogram atomicAdd's return value IS edge i's rank within its dst
// segment — store it; fill_kernel then needs no atomic at all.
__global__ __launch_bounds__(256) void mean_hist_kernel(
    const int* __restrict__ dist, const int* __restrict__ dst,
    int* __restrict__ isum, int* __restrict__ cidx, int* __restrict__ rank) {
  int tid = blockIdx.x * blockDim.x + threadIdx.x;
  int stride = gridDim.x * blockDim.x;
  int acc = 0;
  for (int i = tid; i < N_EDGES; i += stride) {
    acc += dist[i];
    rank[i] = atomicAdd(&cidx[dst[i]], 1);
  }
#pragma unroll
  for (int off = 32; off; off >>= 1) acc += __shfl_down(acc, off);
  if ((threadIdx.x & 63) == 0) atomicAdd(isum, acc);
}

// ---------------- hierarchical scan: A) per-block excl scan + totals ----------------
__global__ __launch_bounds__(256) void scanA_kernel(
    int* __restrict__ c, int* __restrict__ bsum) {
  __shared__ int tmp[256];
  const int t = threadIdx.x;
  const int i = blockIdx.x * 256 + t;
  const int v = (i < N_NODES) ? c[i] : 0;
  tmp[t] = v;
  __syncthreads();
#pragma unroll
  for (int off = 1; off < 256; off <<= 1) {
    int u = (t >= off) ? tmp[t - off] : 0;
    __syncthreads();
    tmp[t] += u;
    __syncthreads();
  }
  if (i < N_NODES) c[i] = tmp[t] - v;          // exclusive within block
  if (t == 255) bsum[blockIdx.x] = tmp[255];   // block total
}

// ---------------- B) scan 196 block totals + pmf LUT (fused tail) ----------------
__global__ __launch_bounds__(256) void scanB_kernel(
    int* __restrict__ bsum, const int* __restrict__ isum, float* __restrict__ lut) {
  __shared__ int tmp[256];
  const int t = threadIdx.x;
  const int v = (t < NB_SCAN) ? bsum[t] : 0;
  tmp[t] = v;
  __syncthreads();
#pragma unroll
  for (int off = 1; off < 256; off <<= 1) {
    int u = (t >= off) ? tmp[t - off] : 0;
    __syncthreads();
    tmp[t] += u;
    __syncthreads();
  }
  if (t < NB_SCAN) bsum[t] = tmp[t] - v;       // exclusive block offsets
  if (t < 100) {                               // lut[d] = pmf(d>>1, mu)
    const float mu = (float)(*isum) * (1.0f / N_EDGES);
    const float k = (float)(t >> 1);
    lut[t] = expf(k * logf(mu) - mu - lgammaf(k + 1.0f));
  }
}

// ---------------- C) add block offsets (cidx becomes exclusive STARTS) ----------------
__global__ __launch_bounds__(256) void scanC_kernel(
    int* __restrict__ c, const int* __restrict__ bsum) {
  const int i = blockIdx.x * 256 + threadIdx.x;
  if (i < N_NODES) c[i] += bsum[blockIdx.x];
}

// ---------------- fill: ATOMIC-FREE CSR fill; one 8B (e,src) pair per edge ----------------
__global__ __launch_bounds__(256) void fill_kernel(
    const int* __restrict__ dst, const int* __restrict__ src,
    const int* __restrict__ dist, const int* __restrict__ rank,
    const float* __restrict__ s1, const float* __restrict__ s2,
    const float* __restrict__ lut, const int* __restrict__ starts,
    float2* __restrict__ epair) {
  int i = blockIdx.x * blockDim.x + threadIdx.x;
  if (i >= N_EDGES) return;
  const int d = dst[i];
  const int s = src[i];
  const float p = lut[dist[i]];
  const float a = s1[s] + s2[d];
  const float ev = p * ((a >= 0.f) ? a : NEG_SLOPE * a);
  const int pos = starts[d] + rank[i];
  epair[pos] = make_float2(ev, __int_as_float(s));
}

// ---------------- node kernel: one wave per dst node ----------------
__global__ __launch_bounds__(256) void node_kernel(
    const int* __restrict__ cidx, const float2* __restrict__ epair,
    const unsigned* __restrict__ zbu, float* __restrict__ out) {
  const int wid = threadIdx.x >> 6, lane = threadIdx.x & 63;
  const int n = blockIdx.x * 4 + wid;
  if (n >= N_NODES) return;
  const int beg = cidx[n];
  const int end = (n + 1 < N_NODES) ? cidx[n + 1] : N_EDGES;
  const int deg = end - beg;

  float2 acc = make_float2(0.f, 0.f);
  if (deg > 0) {
    float m, ssum;
    if (deg <= 64) {
      float e0 = (lane < deg) ? epair[beg + lane].x : -INFINITY;
      m = e0;
#pragma unroll
      for (int off = 32; off; off >>= 1) m = fmaxf(m, __shfl_xor(m, off));
      ssum = expf(e0 - m);   // 0 for invalid lanes
#pragma unroll
      for (int off = 32; off; off >>= 1) ssum += __shfl_xor(ssum, off);
    } else {
      float mm = -INFINITY;
      for (int j = lane; j < deg; j += 64) mm = fmaxf(mm, epair[beg + j].x);
      m = mm;
#pragma unroll
      for (int off = 32; off; off >>= 1) m = fmaxf(m, __shfl_xor(m, off));
      float ss = 0.f;
      for (int j = lane; j < deg; j += 64) ss += expf(epair[beg + j].x - m);
      ssum = ss;
#pragma unroll
      for (int off = 32; off; off >>= 1) ssum += __shfl_xor(ssum, off);
    }
    const float inv = 1.0f / ssum;

    // walk: wave-uniform 8B pair load per edge; unrolled overlapped row gathers
#pragma unroll 4
    for (int jj = 0; jj < deg; ++jj) {
      const float2 pr = epair[beg + jj];
      const float al = expf(pr.x - m) * inv;
      const int   sj = __float_as_int(pr.y);
      const unsigned v = zbu[(size_t)sj * 64 + lane];
      acc.x += al * __uint_as_float((v & 0xFFFFu) << 16);
      acc.y += al * __uint_as_float(v & 0xFFFF0000u);
    }
  }
  *(float2*)&out[(size_t)n * OUT_DIM + lane * 2] = acc;
}

extern "C" void kernel_launch(void* const* d_in, const int* in_sizes, int n_in,
                              void* d_out, int out_size, void* d_ws, size_t ws_size,
                              hipStream_t stream) {
  const float* h    = (const float*)d_in[0];
  const float* fc_w = (const float*)d_in[1];
  const float* attn = (const float*)d_in[2];
  const int*   src  = (const int*)d_in[3];
  const int*   dst  = (const int*)d_in[4];
  const int*   dist = (const int*)d_in[5];
  float* out = (float*)d_out;
  float* ws  = (float*)d_ws;

  // workspace layout (4-byte units), total 4,866,684 words = 19.5 MB
  unsigned short* zb    = (unsigned short*)ws;        // 6,400,000 bf16 = 3,200,000 words
  float*          s1    = ws + 3200000;               //    50,000
  float*          s2    = ws + 3250000;               //    50,000
  int*            cidx  = (int*)(ws + 3300000);       //    50,000 (counts -> starts)
  int*            isum  = (int*)(ws + 3350000);       //         1
  float*          lut   = ws + 3350004;               //       100
  int*            rank  = (int*)(ws + 3350104);       //   500,000
  float2*         epair = (float2*)(ws + 3850104);    //   500,000 pairs (1M words, 8B-aligned)
  unsigned short* Wb    = (unsigned short*)(ws + 4850104); // 32,768 bf16
  int*            bsum  = (int*)(ws + 4866488);       //       196

  hipMemsetAsync(cidx, 0, (size_t)50001 * sizeof(int), stream);  // cidx + isum

  wconv_kernel<<<(IN_DIM * OUT_DIM) / 256, 256, 0, stream>>>(fc_w, Wb);
  gemm_mfma_kernel<<<(N_NODES + 63) / 64, 256, 0, stream>>>(h, Wb, attn, zb, s1, s2);
  mean_hist_kernel<<<256, 256, 0, stream>>>(dist, dst, isum, cidx, rank);
  scanA_kernel<<<NB_SCAN, 256, 0, stream>>>(cidx, bsum);
  scanB_kernel<<<1, 256, 0, stream>>>(bsum, isum, lut);
  scanC_kernel<<<NB_SCAN, 256, 0, stream>>>(cidx, bsum);
  fill_kernel<<<(N_EDGES + 255) / 256, 256, 0, stream>>>(
      dst, src, dist, rank, s1, s2, lut, cidx, epair);
  node_kernel<<<(N_NODES + 3) / 4, 256, 0, stream>>>(
      cidx, epair, (const unsigned*)zb, out);
}